// Round 7
// baseline (2245.034 us; speedup 1.0000x reference)
//
#include <hip/hip_runtime.h>
#include <stdint.h>

#define TT 2048
#define BB 128
#define DD 100
#define HH 100
#define GG 300   // 3*H, PyTorch gate order [r,z,n]
#define NT 31
#define NEGV (-10000.0f)

#define REP25(M) M(0) M(1) M(2) M(3) M(4) M(5) M(6) M(7) M(8) M(9) M(10) M(11) \
                 M(12) M(13) M(14) M(15) M(16) M(17) M(18) M(19) M(20) M(21) M(22) M(23) M(24)
#define REP31(M) M(0) M(1) M(2) M(3) M(4) M(5) M(6) M(7) M(8) M(9) M(10) M(11) \
                 M(12) M(13) M(14) M(15) M(16) M(17) M(18) M(19) M(20) M(21) M(22) M(23) \
                 M(24) M(25) M(26) M(27) M(28) M(29) M(30)
#define REP8(M)  M(0) M(1) M(2) M(3) M(4) M(5) M(6) M(7)

#define RL(v, k) __int_as_float(__builtin_amdgcn_readlane(__float_as_int(v), (k)))

// ---------------------------------------------------------------------------
// Kernel 1: gi[dir][t][g] = x_dir(t) @ w_ih^T + b_ih  for batch row `seq`.
// ---------------------------------------------------------------------------
__global__ __launch_bounds__(320) void gi_kernel(
    const float* __restrict__ sent, const int* __restrict__ seqp,
    const float* __restrict__ w_ih_f, const float* __restrict__ b_ih_f,
    const float* __restrict__ w_ih_b, const float* __restrict__ b_ih_b,
    float* __restrict__ gi)
{
    const int t   = blockIdx.x;
    const int dir = blockIdx.y;
    const int j   = threadIdx.x;
    const int seq = seqp[0];
    const int ts  = dir ? (TT - 1 - t) : t;
    __shared__ __align__(16) float x_s[DD];
    if (j < DD) x_s[j] = sent[((size_t)ts * BB + seq) * DD + j];
    __syncthreads();
    if (j < GG) {
        const float* w = dir ? w_ih_b : w_ih_f;
        const float* b = dir ? b_ih_b : b_ih_f;
        const float4* w4 = (const float4*)(w + j * DD);
        const float4* x4 = (const float4*)x_s;
        float a0 = 0.f, a1 = 0.f, a2 = 0.f, a3 = 0.f;
        #pragma unroll
        for (int k = 0; k < DD / 4; k++) {
            float4 wv = w4[k], xv = x4[k];
            a0 += wv.x * xv.x; a1 += wv.y * xv.y;
            a2 += wv.z * xv.z; a3 += wv.w * xv.w;
        }
        gi[((size_t)dir * TT + t) * GG + j] = b[j] + (a0 + a1) + (a2 + a3);
    }
}

// ---------------------------------------------------------------------------
// Kernel 2: sequential GRU. 512 threads = 8 waves (2/SIMD), one block/dir.
// Wave pair (2q, 2q+1) owns k-quarter q; weights = 75 named scalars per lane,
// PINNED via opaque asm (compiler rematerialized the loads in R2-R6:
// VGPR_Count 64-68 < weight count => per-step global reloads + barrier
// drains were the bottleneck). amdgpu_waves_per_eu(2,2) raises the VGPR
// budget to 256 so pinning cannot turn into scratch spill.
// gi is staged through LDS in 8-step batches so the pre-barrier vmcnt(0)
// drain pays the LLC round-trip once per 8 steps, not every step.
// ---------------------------------------------------------------------------
__global__ __launch_bounds__(512) __attribute__((amdgpu_waves_per_eu(2, 2)))
void gru_seq_kernel(
    const float* __restrict__ gi,
    const float* __restrict__ w_hh_f, const float* __restrict__ b_hh_f,
    const float* __restrict__ w_hh_b, const float* __restrict__ b_hh_b,
    const float* __restrict__ w_out,
    float* __restrict__ pfeat)           // [2][TT][NT], original time order
{
    const int dir  = blockIdx.x;
    const int tid  = threadIdx.x;
    const int wave = tid >> 6, lane = tid & 63;
    const int q    = wave >> 1;
    const bool isA = !(wave & 1);
    const int k0   = q * 25;
    const float* w_hh = dir ? w_hh_b : w_hh_f;
    const float* b_hh = dir ? b_hh_b : b_hh_f;
    const float* gid  = gi + (size_t)dir * TT * GG;
    float* pf = pfeat + (size_t)dir * TT * NT;

    __shared__ float part[2][4][384];        // [buf][quarter][slot] 12.3 KB
    __shared__ __align__(16) float gibuf[2][8][GG];  // gi staging, 19.2 KB

    const int s0 = (isA ? 0 : 64) + lane;
    const int s1 = (isA ? 128 : 192) + lane;
    const int s2 = (isA ? 256 : 320) + lane;

    const float* r0 = w_hh + s0 * DD + k0;
    const float* r1 = w_hh + s1 * DD + k0;
    const int wrow = (s2 - GG) < (NT - 1) ? (s2 - GG) : (NT - 1);
    const float* r2 = (s2 < GG) ? (w_hh + s2 * DD + k0)
                                : (w_out + wrow * (2 * HH) + dir * HH + k0);

    // ---- 75 named-scalar weights, pinned non-rematerializable ----
    #define DECLW(i) float w0_##i, w1_##i, w2_##i;
    REP25(DECLW)
    #define LDW(i) w0_##i = r0[i]; w1_##i = r1[i]; w2_##i = r2[i];
    REP25(LDW)
    asm volatile("" : "+v"(w0_0),"+v"(w0_1),"+v"(w0_2),"+v"(w0_3),"+v"(w0_4),
                      "+v"(w0_5),"+v"(w0_6),"+v"(w0_7),"+v"(w0_8),"+v"(w0_9),
                      "+v"(w0_10),"+v"(w0_11),"+v"(w0_12),"+v"(w0_13),"+v"(w0_14),
                      "+v"(w0_15),"+v"(w0_16),"+v"(w0_17),"+v"(w0_18),"+v"(w0_19),
                      "+v"(w0_20),"+v"(w0_21),"+v"(w0_22),"+v"(w0_23),"+v"(w0_24));
    asm volatile("" : "+v"(w1_0),"+v"(w1_1),"+v"(w1_2),"+v"(w1_3),"+v"(w1_4),
                      "+v"(w1_5),"+v"(w1_6),"+v"(w1_7),"+v"(w1_8),"+v"(w1_9),
                      "+v"(w1_10),"+v"(w1_11),"+v"(w1_12),"+v"(w1_13),"+v"(w1_14),
                      "+v"(w1_15),"+v"(w1_16),"+v"(w1_17),"+v"(w1_18),"+v"(w1_19),
                      "+v"(w1_20),"+v"(w1_21),"+v"(w1_22),"+v"(w1_23),"+v"(w1_24));
    asm volatile("" : "+v"(w2_0),"+v"(w2_1),"+v"(w2_2),"+v"(w2_3),"+v"(w2_4),
                      "+v"(w2_5),"+v"(w2_6),"+v"(w2_7),"+v"(w2_8),"+v"(w2_9),
                      "+v"(w2_10),"+v"(w2_11),"+v"(w2_12),"+v"(w2_13),"+v"(w2_14),
                      "+v"(w2_15),"+v"(w2_16),"+v"(w2_17),"+v"(w2_18),"+v"(w2_19),
                      "+v"(w2_20),"+v"(w2_21),"+v"(w2_22),"+v"(w2_23),"+v"(w2_24));

    // ---- activation lanes: lane < 25 in EVERY wave, row r = k0 + lane ----
    const int r = k0 + lane;
    float bhr = 0.f, bhz = 0.f, bhn = 0.f;
    if (lane < 25) { bhr = b_hh[r]; bhz = b_hh[HH + r]; bhn = b_hh[2 * HH + r]; }

    // ---- pfeat lanes: wave 1, lanes 32..62 -> p = lane-32 ----
    const int  p     = lane - 32;
    const bool is_pf = (wave == 1) && (p >= 0) && (p < NT);
    #define DECLPH(i) float ph##i = 0.f;
    REP8(DECLPH)

    float hreg = 0.f;                    // lane L<25: h[k0+L]

    // ---- gi staging: 8 steps (2400 floats = 600 float4) per batch ----
    auto stage = [&](int tbase, int nb) {
        const float4* src = (const float4*)(gid + (size_t)tbase * GG);
        float4* dst = (float4*)&gibuf[nb][0][0];
        for (int i = tid; i < 600; i += 512) dst[i] = src[i];
    };
    stage(0, 0);                         // prologue; visible at step 0's barrier

    #define DOTK(i) { float hk = RL(hreg, i);              \
        a0 = fmaf(hk, w0_##i, a0);                          \
        a1 = fmaf(hk, w1_##i, a1);                          \
        a2 = fmaf(hk, w2_##i, a2); }

    #define GRU_STEP(TIDX, BUF, SLOT, GB) {                                  \
        float a0 = 0.f, a1 = 0.f, a2 = 0.f;                                  \
        REP25(DOTK)                                                          \
        part[BUF][q][s0] = a0;                                               \
        part[BUF][q][s1] = a1;                                               \
        part[BUF][q][s2] = a2;                                               \
        __syncthreads();                                                     \
        if (lane < 25) {                                                     \
            float pr = part[BUF][0][r] + part[BUF][1][r]                     \
                     + part[BUF][2][r] + part[BUF][3][r];                    \
            float pz = part[BUF][0][HH + r] + part[BUF][1][HH + r]           \
                     + part[BUF][2][HH + r] + part[BUF][3][HH + r];          \
            float pn = part[BUF][0][2 * HH + r] + part[BUF][1][2 * HH + r]   \
                     + part[BUF][2][2 * HH + r] + part[BUF][3][2 * HH + r];  \
            float gr = gibuf[GB][(TIDX) & 7][r];                             \
            float gz = gibuf[GB][(TIDX) & 7][HH + r];                        \
            float gn = gibuf[GB][(TIDX) & 7][2 * HH + r];                    \
            float xr  = pr + bhr + gr;                                       \
            float xz  = pz + bhz + gz;                                       \
            float ghn = pn + bhn;                                            \
            float rr  = 1.f / (1.f + __expf(-xr));                           \
            float zz  = 1.f / (1.f + __expf(-xz));                           \
            float pre = gn + rr * ghn;                                       \
            pre = fmaxf(fminf(pre, 40.f), -40.f);                            \
            float e2  = __expf(-2.f * pre);                                  \
            float nn  = (1.f - e2) / (1.f + e2);                             \
            hreg = (1.f - zz) * nn + zz * hreg;                              \
        }                                                                    \
        if (is_pf && (TIDX) > 0) {                                           \
            ph##SLOT = part[BUF][0][GG + p] + part[BUF][1][GG + p]           \
                     + part[BUF][2][GG + p] + part[BUF][3][GG + p];          \
        }                                                                    \
    }

    #define PHST(i) pf[(size_t)(dir ? (TT - 1 - (tb + i)) : (tb + i)) * NT + p] = ph##i;

    for (int tt = 0; tt < TT; tt += 8) {
        const int gb = (tt >> 3) & 1;
        stage(tt + 8, gb ^ 1);           // next batch; drains at step tt's barrier
        GRU_STEP(tt + 0, 0, 7, gb)
        if (is_pf && tt >= 8) { int tb = tt - 8; REP8(PHST) }
        GRU_STEP(tt + 1, 1, 0, gb)
        GRU_STEP(tt + 2, 0, 1, gb)
        GRU_STEP(tt + 3, 1, 2, gb)
        GRU_STEP(tt + 4, 0, 3, gb)
        GRU_STEP(tt + 5, 1, 4, gb)
        GRU_STEP(tt + 6, 0, 5, gb)
        GRU_STEP(tt + 7, 1, 6, gb)
    }

    // ---- epilogue: feat of time TT-1 from final h ----
    {
        float a2 = 0.f;
        #define DOT2K(i) a2 = fmaf(RL(hreg, i), w2_##i, a2);
        REP25(DOT2K)
        part[0][q][s2] = a2;
        __syncthreads();
        if (is_pf) {
            ph7 = part[0][0][GG + p] + part[0][1][GG + p]
                + part[0][2][GG + p] + part[0][3][GG + p];
            int tb = TT - 8;
            REP8(PHST)
        }
    }
}

// ---------------------------------------------------------------------------
// Kernel 3a: serial Viterbi fv scan (values only; max is order-exact).
// Single wave, zero barriers, tree-max, trans row pinned in VGPRs.
// fvg[t] = fv BEFORE step t (slot 0 = init).
// ---------------------------------------------------------------------------
__global__ __launch_bounds__(64) __attribute__((amdgpu_waves_per_eu(1)))
void vit_scan_kernel(
    const float* __restrict__ pfeat, const float* __restrict__ mask,
    const int* __restrict__ seqp, const float* __restrict__ trans,
    const float* __restrict__ b_out,
    float* __restrict__ fvg, int* __restrict__ meta, float* __restrict__ out)
{
    const int lane = threadIdx.x;
    const int ln   = (lane < NT) ? lane : (NT - 1);   // clamped for loads
    const float* mrow = mask + (size_t)seqp[0] * TT;
    const float* pff = pfeat;
    const float* pfb = pfeat + (size_t)TT * NT;

    #define DECLTR(i) float tr##i = trans[ln * NT + i];
    REP31(DECLTR)
    asm volatile("" : "+v"(tr0),"+v"(tr1),"+v"(tr2),"+v"(tr3),"+v"(tr4),
                      "+v"(tr5),"+v"(tr6),"+v"(tr7),"+v"(tr8),"+v"(tr9),
                      "+v"(tr10),"+v"(tr11),"+v"(tr12),"+v"(tr13),"+v"(tr14),
                      "+v"(tr15),"+v"(tr16),"+v"(tr17),"+v"(tr18),"+v"(tr19),
                      "+v"(tr20),"+v"(tr21),"+v"(tr22),"+v"(tr23),"+v"(tr24),
                      "+v"(tr25),"+v"(tr26),"+v"(tr27),"+v"(tr28),"+v"(tr29),
                      "+v"(tr30));
    const float bo = b_out[ln];

    float fv = (lane == 0) ? 0.f : NEGV;
    fvg[lane] = fv;                                   // slot 0 = init

    float ffr[8], fbr[8], mr[8];
    #pragma unroll
    for (int q = 0; q < 8; q++) {
        ffr[q] = pff[q * NT + ln]; fbr[q] = pfb[q * NT + ln]; mr[q] = mrow[q];
    }

    for (int t = 0; t < TT; t += 8) {
        #pragma unroll
        for (int q = 0; q < 8; q++) {
            float fcur = ffr[q] + fbr[q] + bo;
            float mcur = mr[q];
            int tp = t + q + 8; tp = (tp < TT) ? tp : (TT - 1);
            ffr[q] = pff[tp * NT + ln]; fbr[q] = pfb[tp * NT + ln]; mr[q] = mrow[tp];
            #define VADD(i) float v##i = RL(fv, i) + tr##i;
            REP31(VADD)
            #undef VADD
            v0  = fmaxf(v0,  v16); v1  = fmaxf(v1,  v17); v2  = fmaxf(v2,  v18);
            v3  = fmaxf(v3,  v19); v4  = fmaxf(v4,  v20); v5  = fmaxf(v5,  v21);
            v6  = fmaxf(v6,  v22); v7  = fmaxf(v7,  v23); v8  = fmaxf(v8,  v24);
            v9  = fmaxf(v9,  v25); v10 = fmaxf(v10, v26); v11 = fmaxf(v11, v27);
            v12 = fmaxf(v12, v28); v13 = fmaxf(v13, v29); v14 = fmaxf(v14, v30);
            v0 = fmaxf(v0, v8);  v1 = fmaxf(v1, v9);  v2 = fmaxf(v2, v10);
            v3 = fmaxf(v3, v11); v4 = fmaxf(v4, v12); v5 = fmaxf(v5, v13);
            v6 = fmaxf(v6, v14); v7 = fmaxf(v7, v15);
            v0 = fmaxf(v0, v4); v1 = fmaxf(v1, v5); v2 = fmaxf(v2, v6); v3 = fmaxf(v3, v7);
            v0 = fmaxf(v0, v2); v1 = fmaxf(v1, v3);
            float m = fmaxf(v0, v1);
            float cand = m + fcur;
            fv = (mcur > 0.f) ? cand : fv;
            fvg[(t + q + 1) * 64 + lane] = fv;
        }
    }

    // final argmax, strict '>' ascending = first-max
    float fbest = RL(fv, 0);
    int ftag = 0;
    #pragma unroll
    for (int q = 1; q < NT; q++) {
        float s = RL(fv, q);
        if (s > fbest) { fbest = s; ftag = q; }
    }
    if (lane == 0) { out[0] = fbest; meta[0] = ftag; }
}

// ---------------------------------------------------------------------------
// Kernel 3b: parallel backpointer pass. Block b: t in [64b, 64b+64), 16 waves
// x 4 t's each. Recomputes argmax from stored fv (bit-exact same operands),
// exact first-max; wave 0 composes the block's 64 backpointer maps.
// ---------------------------------------------------------------------------
__global__ __launch_bounds__(1024) void vit_bp_kernel(
    const float* __restrict__ fvg, const float* __restrict__ mask,
    const int* __restrict__ seqp, const float* __restrict__ trans,
    uint8_t* __restrict__ bpg, uint8_t* __restrict__ gmapg)
{
    const int b    = blockIdx.x;
    const int tid  = threadIdx.x;
    const int wave = tid >> 6, lane = tid & 63;
    const int j    = lane & 31;
    const int jr   = (j < NT) ? j : (NT - 1);
    const float* mrow = mask + (size_t)seqp[0] * TT;

    __shared__ int bpl[64][32];

    float trj[NT];
    #pragma unroll
    for (int q = 0; q < NT; q++) trj[q] = trans[jr * NT + q];

    #pragma unroll
    for (int q4 = 0; q4 < 4; q4++) {
        const int t = b * 64 + wave * 4 + q4;
        float fvp = fvg[t * 64 + lane];          // lane p holds fv_prev[p]
        float mcur = mrow[t];
        float best = RL(fvp, 0) + trj[0];
        int bi = 0;
        #pragma unroll
        for (int q = 1; q < NT; q++) {
            float s = RL(fvp, q) + trj[q];
            if (s > best) { best = s; bi = q; }  // ascending strict '>' = first-max
        }
        int bpn = (mcur > 0.f) ? bi : j;
        if (j == 31) bpn = 31;
        if (lane < 32) {
            bpl[wave * 4 + q4][lane] = bpn;
            if (j < NT) bpg[(size_t)t * NT + j] = (uint8_t)bpn;
        }
    }
    __syncthreads();
    if (wave == 0) {
        int G = j;
        for (int i = 0; i < 64; i++) {
            int bpv = bpl[i][j];
            G = __shfl(G, bpv);                  // G_new[j] = G_old[bp_i[j]]
        }
        if (lane < 32) gmapg[b * 32 + lane] = (uint8_t)G;
    }
}

// ---------------------------------------------------------------------------
// Kernel 3c: backtrack. Loads all backpointers into LDS, composes the 32
// block maps serially (lane 0), then 32 lanes backtrack 64 steps each.
// ---------------------------------------------------------------------------
__global__ __launch_bounds__(64) void vit_back_kernel(
    const uint8_t* __restrict__ bpg, const uint8_t* __restrict__ gmapg,
    const int* __restrict__ meta, float* __restrict__ out)
{
    const int tid = threadIdx.x;
    __shared__ uint8_t bps[TT * NT];     // 63488 B
    __shared__ uint8_t gm[32 * 32];
    __shared__ uint8_t echk[32];

    const uint32_t* src = (const uint32_t*)bpg;
    uint32_t* dst = (uint32_t*)bps;
    for (int i = tid; i < TT * NT / 4; i += 64) dst[i] = src[i];
    for (int i = tid; i < 1024 / 4; i += 64)
        ((uint32_t*)gm)[i] = ((const uint32_t*)gmapg)[i];
    __syncthreads();

    if (tid == 0) {
        int tag = meta[0];
        for (int b = 31; b >= 0; b--) { echk[b] = (uint8_t)tag; tag = gm[b * 32 + tag]; }
    }
    __syncthreads();
    if (tid < 32) {
        int tag = echk[tid];
        for (int i = 63; i >= 0; i--) {
            int t = tid * 64 + i;
            out[1 + t] = (float)tag;
            tag = bps[t * NT + tag];
        }
    }
}

// ---------------------------------------------------------------------------
extern "C" void kernel_launch(void* const* d_in, const int* in_sizes, int n_in,
                              void* d_out, int out_size, void* d_ws, size_t ws_size,
                              hipStream_t stream) {
    const float* sent   = (const float*)d_in[0];
    const float* mask   = (const float*)d_in[1];
    const float* w_ih_f = (const float*)d_in[2];
    const float* w_hh_f = (const float*)d_in[3];
    const float* b_ih_f = (const float*)d_in[4];
    const float* b_hh_f = (const float*)d_in[5];
    const float* w_ih_b = (const float*)d_in[6];
    const float* w_hh_b = (const float*)d_in[7];
    const float* b_ih_b = (const float*)d_in[8];
    const float* b_hh_b = (const float*)d_in[9];
    const float* w_out  = (const float*)d_in[10];
    const float* b_out  = (const float*)d_in[11];
    const float* trans  = (const float*)d_in[12];
    const int*   seqp   = (const int*)d_in[14];
    float* out = (float*)d_out;

    // ws layout (floats): gi[2*TT*300] | pfeat[2*TT*31] | fvg[(TT+1)*64] |
    //                     bpg (TT*31 bytes) | gmapg (1024 bytes) | meta
    float* gi    = (float*)d_ws;
    float* pfeat = gi + (size_t)2 * TT * GG;
    float* fvg   = pfeat + (size_t)2 * TT * NT;
    float* bpf   = fvg + (size_t)(TT + 1) * 64;
    uint8_t* bpg   = (uint8_t*)bpf;
    uint8_t* gmapg = bpg + (size_t)TT * NT;
    int*     meta  = (int*)(gmapg + 1024);

    gi_kernel<<<dim3(TT, 2), 320, 0, stream>>>(sent, seqp, w_ih_f, b_ih_f,
                                               w_ih_b, b_ih_b, gi);
    gru_seq_kernel<<<2, 512, 0, stream>>>(gi, w_hh_f, b_hh_f, w_hh_b, b_hh_b,
                                          w_out, pfeat);
    vit_scan_kernel<<<1, 64, 0, stream>>>(pfeat, mask, seqp, trans, b_out,
                                          fvg, meta, out);
    vit_bp_kernel<<<32, 1024, 0, stream>>>(fvg, mask, seqp, trans, bpg, gmapg);
    vit_back_kernel<<<1, 64, 0, stream>>>(bpg, gmapg, meta, out);
}